// Round 4
// baseline (184.118 us; speedup 1.0000x reference)
//
#include <hip/hip_runtime.h>
#include <hip/hip_bf16.h>

constexpr int N_NODES = 40000;
constexpr int N_EDGES = 640000;
constexpr int D = 128;
constexpr float BN_EPS = 1e-5f;
constexpr int CAP = 128;          // per-node edge bucket capacity (max deg ~40)
constexpr int NCOLOR = 8;         // XCD colors
constexpr int NODES_PER_COLOR = N_NODES / NCOLOR;   // 5000
constexpr int FILL_BLOCKS = 2560; // 8 colors x 320 ranks
constexpr int COLOR_STRIDE = (FILL_BLOCKS / NCOLOR) * 256;  // 81920
constexpr int GG_BLOCKS = N_NODES / 64;             // 625 gather+gemm blocks

typedef __attribute__((ext_vector_type(8))) short short8;
typedef __attribute__((ext_vector_type(4))) float f32x4;
typedef __attribute__((ext_vector_type(2))) float f32x2;

__device__ __forceinline__ unsigned bf16_rne(float f) {
    unsigned b = __float_as_uint(f);
    return (b + 0x7FFFu + ((b >> 16) & 1u)) >> 16;
}
__device__ __forceinline__ float bflo(unsigned w) { return __uint_as_float(w << 16); }
__device__ __forceinline__ float bfhi(unsigned w) { return __uint_as_float(w & 0xFFFF0000u); }

// ---------------------------------------------------------------------------
// K1: fused h->bf16 + h->fp8 / W->frag-major conversion + XCD-COLORED bucket
// fill. (unchanged from round 3)
// ---------------------------------------------------------------------------
__global__ __launch_bounds__(256) void cvt_fill_kernel(
        const int* __restrict__ dst,
        const int* __restrict__ src,
        int* __restrict__ cursor,
        int* __restrict__ esrc,
        const float4* __restrict__ h4,
        uint4* __restrict__ hb4,
        uint2* __restrict__ hb8,
        const float* __restrict__ Wself,
        const float* __restrict__ Wneigh,
        uint4* __restrict__ wfrag) {
    int gid = blockIdx.x * blockDim.x + threadIdx.x;

    if (gid < N_EDGES) {
        float4 a = h4[2 * gid];
        float4 b = h4[2 * gid + 1];
        uint4 o;
        o.x = bf16_rne(a.x) | (bf16_rne(a.y) << 16);
        o.y = bf16_rne(a.z) | (bf16_rne(a.w) << 16);
        o.z = bf16_rne(b.x) | (bf16_rne(b.y) << 16);
        o.w = bf16_rne(b.z) | (bf16_rne(b.w) << 16);
        hb4[gid] = o;
        unsigned w0 = __builtin_amdgcn_cvt_pk_fp8_f32(a.x, a.y, 0, false);
        w0 = __builtin_amdgcn_cvt_pk_fp8_f32(a.z, a.w, w0, true);
        unsigned w1 = __builtin_amdgcn_cvt_pk_fp8_f32(b.x, b.y, 0, false);
        w1 = __builtin_amdgcn_cvt_pk_fp8_f32(b.z, b.w, w1, true);
        uint2 o8; o8.x = w0; o8.y = w1;
        hb8[gid] = o8;
    }
    // W -> frag-major bf16: granule G=(ct*8+kt)*64+kg*16+n holds j=0..7 of
    // Wcat[k=kt*32+kg*8+j][col=ct*16+n], Wcat=[Wself;Wneigh] (K=256).
    if (gid < 4096) {
        int G = gid;
        int l = G & 63;
        int tile = G >> 6;
        int kg = l >> 4, n = l & 15;
        int ct = tile >> 3, kt = tile & 7;
        int k0 = kt * 32 + kg * 8;
        int col = ct * 16 + n;
        unsigned w[8];
        #pragma unroll
        for (int j = 0; j < 8; j++) {
            int k = k0 + j;
            float v = (k < D) ? Wself[(size_t)k * D + col]
                              : Wneigh[(size_t)(k - D) * D + col];
            w[j] = bf16_rne(v);
        }
        uint4 ow;
        ow.x = w[0] | (w[1] << 16);
        ow.y = w[2] | (w[3] << 16);
        ow.z = w[4] | (w[5] << 16);
        ow.w = w[6] | (w[7] << 16);
        wfrag[G] = ow;
    }

    // colored bucket fill
    int c = blockIdx.x & (NCOLOR - 1);
    int lo = c * NODES_PER_COLOR;
    int hi = lo + NODES_PER_COLOR;
    int base = (blockIdx.x >> 3) * 256 + threadIdx.x;
    for (int e = base; e < N_EDGES; e += COLOR_STRIDE) {
        int t = dst[e];
        if (t >= lo && t < hi) {
            int s = src[e];
            int p = atomicAdd(&cursor[t], 1);
            if (p < CAP) esrc[t * CAP + p] = s;
        }
    }
}

// ---------------------------------------------------------------------------
// K2': MERGED gather + dual GEMM. 625 blocks x 4 waves; block owns rows
// [blk*64, blk*64+64), all 128 cols. Each wave gathers fp8 neighbor means
// for its 16 rows into a swizzled LDS tile (ntile), then MFMA consumes
// A-neigh frags from ntile and A-self frags from hb4. W staged per col-half
// (32KB); LDS total 49KB -> 3 blocks/CU. Eliminates hnb round-trip + one
// dispatch. Epilogue identical to previous K3 (relu+snorm+preb+BN partials).
// ntile layout: row r (0..63), 16 uint4 slots; slot s stores cols
// [s*8, s*8+8) bf16, stored at slot s ^ (r&7)  (bank swizzle).
// ---------------------------------------------------------------------------
__global__ __launch_bounds__(256) void gemm_gather_kernel(
        const uint4* __restrict__ hb4,
        const uint4* __restrict__ hb8q,   // 8 uint4 per node row (128 fp8)
        const int* __restrict__ cursor,
        const int* __restrict__ esrc,
        const uint4* __restrict__ wfrag,
        const float* __restrict__ snorm,
        const float* __restrict__ bias,
        ushort* __restrict__ preb,
        float* __restrict__ sums,
        float* __restrict__ sumsq) {
    __shared__ uint4 ldsW[2048];      // 32KB: one col-half of W
    __shared__ uint4 ntile[1024];     // 16KB: 64 rows x 128 cols bf16
    __shared__ float sums_l[128];
    __shared__ float sumsq_l[128];

    int t = threadIdx.x;
    int lane = t & 63;
    int wid = t >> 6;
    int row_base = blockIdx.x * 64 + wid * 16;

    if (t < 128) { sums_l[t] = 0.f; sumsq_l[t] = 0.f; }

    // stage W col-half 0 (hides under the gather)
    #pragma unroll
    for (int i = 0; i < 8; i++) ldsW[i * 256 + t] = wfrag[i * 256 + t];

    // ---- gather phase: wave computes neighbor means for its 16 rows ----
    int g  = lane & 7;        // 16-col group
    int es = lane >> 3;       // 8 edge slices
    for (int i = 0; i < 16; i++) {
        int node = row_base + i;
        int deg = cursor[node];
        int cnt = deg < CAP ? deg : CAP;
        const int* bucket = esrc + node * CAP;
        float acc[16];
        #pragma unroll
        for (int q = 0; q < 16; q++) acc[q] = 0.f;
        for (int j = es; j < cnt; j += 8) {
            int a = bucket[j];
            uint4 v = hb8q[(size_t)a * 8 + g];
            f32x2 f;
            f = __builtin_amdgcn_cvt_pk_f32_fp8(v.x, false); acc[0]  += f.x; acc[1]  += f.y;
            f = __builtin_amdgcn_cvt_pk_f32_fp8(v.x, true);  acc[2]  += f.x; acc[3]  += f.y;
            f = __builtin_amdgcn_cvt_pk_f32_fp8(v.y, false); acc[4]  += f.x; acc[5]  += f.y;
            f = __builtin_amdgcn_cvt_pk_f32_fp8(v.y, true);  acc[6]  += f.x; acc[7]  += f.y;
            f = __builtin_amdgcn_cvt_pk_f32_fp8(v.z, false); acc[8]  += f.x; acc[9]  += f.y;
            f = __builtin_amdgcn_cvt_pk_f32_fp8(v.z, true);  acc[10] += f.x; acc[11] += f.y;
            f = __builtin_amdgcn_cvt_pk_f32_fp8(v.w, false); acc[12] += f.x; acc[13] += f.y;
            f = __builtin_amdgcn_cvt_pk_f32_fp8(v.w, true);  acc[14] += f.x; acc[15] += f.y;
        }
        #pragma unroll
        for (int q = 0; q < 16; q++) {
            acc[q] += __shfl_xor(acc[q], 8);
            acc[q] += __shfl_xor(acc[q], 16);
            acc[q] += __shfl_xor(acc[q], 32);
        }
        // es==0 lane of each g packs & writes both uint4 slots (static idx)
        if (es == 0) {
            float rd = 1.0f / (float)(deg > 1 ? deg : 1);
            uint4 o0, o1;
            o0.x = bf16_rne(acc[0] * rd)  | (bf16_rne(acc[1] * rd)  << 16);
            o0.y = bf16_rne(acc[2] * rd)  | (bf16_rne(acc[3] * rd)  << 16);
            o0.z = bf16_rne(acc[4] * rd)  | (bf16_rne(acc[5] * rd)  << 16);
            o0.w = bf16_rne(acc[6] * rd)  | (bf16_rne(acc[7] * rd)  << 16);
            o1.x = bf16_rne(acc[8] * rd)  | (bf16_rne(acc[9] * rd)  << 16);
            o1.y = bf16_rne(acc[10] * rd) | (bf16_rne(acc[11] * rd) << 16);
            o1.z = bf16_rne(acc[12] * rd) | (bf16_rne(acc[13] * rd) << 16);
            o1.w = bf16_rne(acc[14] * rd) | (bf16_rne(acc[15] * rd) << 16);
            int rloc = wid * 16 + i;
            int base = rloc * 16;
            int sw = rloc & 7;
            ntile[base + ((g * 2)     ^ sw)] = o0;
            ntile[base + ((g * 2 + 1) ^ sw)] = o1;
        }
    }
    __syncthreads();   // ntile complete + W half-0 staged

    // ---- MFMA phase ----
    int n  = lane & 15;
    int kg = lane >> 4;
    int row = row_base + n;

    uint4 a_s[4], a_n[4];
    #pragma unroll
    for (int kt = 0; kt < 4; kt++)
        a_s[kt] = hb4[(size_t)row * 16 + kt * 4 + kg];
    {
        int rloc = wid * 16 + n;
        int base = rloc * 16;
        int sw = rloc & 7;
        #pragma unroll
        for (int kt = 0; kt < 4; kt++)
            a_n[kt] = ntile[base + ((kt * 4 + kg) ^ sw)];
    }

    f32x4 acc8[8];
    #pragma unroll
    for (int q = 0; q < 8; q++) acc8[q] = (f32x4){0.f, 0.f, 0.f, 0.f};

    #pragma unroll
    for (int lt = 0; lt < 4; lt++) {
        #pragma unroll
        for (int kt = 0; kt < 8; kt++) {
            short8 b = __builtin_bit_cast(short8, ldsW[(lt * 8 + kt) * 64 + lane]);
            short8 a = __builtin_bit_cast(short8, (kt < 4) ? a_s[kt] : a_n[kt - 4]);
            acc8[lt] = __builtin_amdgcn_mfma_f32_16x16x32_bf16(a, b, acc8[lt], 0, 0, 0);
        }
    }
    __syncthreads();   // done reading W half-0
    #pragma unroll
    for (int i = 0; i < 8; i++) ldsW[i * 256 + t] = wfrag[2048 + i * 256 + t];
    __syncthreads();   // W half-1 staged
    #pragma unroll
    for (int lt = 0; lt < 4; lt++) {
        #pragma unroll
        for (int kt = 0; kt < 8; kt++) {
            short8 b = __builtin_bit_cast(short8, ldsW[(lt * 8 + kt) * 64 + lane]);
            short8 a = __builtin_bit_cast(short8, (kt < 4) ? a_s[kt] : a_n[kt - 4]);
            acc8[4 + lt] = __builtin_amdgcn_mfma_f32_16x16x32_bf16(a, b, acc8[4 + lt], 0, 0, 0);
        }
    }

    // ---- epilogue: relu + snorm + preb + BN partials (as previous K3) ----
    float snv[4];
    #pragma unroll
    for (int r = 0; r < 4; r++) snv[r] = snorm[row_base + kg * 4 + r];

    #pragma unroll
    for (int hh = 0; hh < 2; hh++) {
        #pragma unroll
        for (int lt = 0; lt < 4; lt++) {
            int col = hh * 64 + lt * 16 + n;
            float bb = bias[col];
            float csum = 0.f, csq = 0.f;
            #pragma unroll
            for (int r = 0; r < 4; r++) {
                int rr = row_base + kg * 4 + r;
                float v = acc8[hh * 4 + lt][r] + bb;
                v = fmaxf(v, 0.f);
                v *= snv[r];
                preb[(size_t)rr * D + col] = (ushort)bf16_rne(v);
                csum += v;
                csq += v * v;
            }
            csum += __shfl_xor(csum, 16); csq += __shfl_xor(csq, 16);
            csum += __shfl_xor(csum, 32); csq += __shfl_xor(csq, 32);
            if (kg == 0) {
                atomicAdd(&sums_l[col], csum);
                atomicAdd(&sumsq_l[col], csq);
            }
        }
    }
    __syncthreads();
    if (t < 128) {
        atomicAdd(&sums[t], sums_l[t]);
        atomicAdd(&sumsq[t], sumsq_l[t]);
    }
}

// ---------------------------------------------------------------------------
// K4: finalize: out = h + (pre - mean)*scale + beta (unchanged)
// ---------------------------------------------------------------------------
__global__ __launch_bounds__(256) void final_kernel(
        const float4* __restrict__ h4,
        const float4* __restrict__ sums4,
        const float4* __restrict__ sumsq4,
        const float4* __restrict__ gamma4,
        const float4* __restrict__ beta4,
        const uint4* __restrict__ preb4,
        float4* __restrict__ out4) {
    int idx = blockIdx.x * blockDim.x + threadIdx.x;
    int total = N_NODES * D / 8;
    if (idx >= total) return;
    int g = idx & 15;                       // col-group of 8 within the row
    const float invN = 1.0f / (float)N_NODES;

    float4 s0 = sums4[2 * g],  s1 = sums4[2 * g + 1];
    float4 q0 = sumsq4[2 * g], q1 = sumsq4[2 * g + 1];
    float4 g0 = gamma4[2 * g], g1 = gamma4[2 * g + 1];
    float4 b0 = beta4[2 * g],  b1 = beta4[2 * g + 1];

    uint4 p = preb4[idx];
    float4 h0 = h4[2 * idx], h1 = h4[2 * idx + 1];
    float4 o0, o1;
    float m, var, sc;

    m = s0.x * invN; var = q0.x * invN - m * m; sc = g0.x * rsqrtf(var + BN_EPS);
    o0.x = h0.x + (bflo(p.x) - m) * sc + b0.x;
    m = s0.y * invN; var = q0.y * invN - m * m; sc = g0.y * rsqrtf(var + BN_EPS);
    o0.y = h0.y + (bfhi(p.x) - m) * sc + b0.y;
    m = s0.z * invN; var = q0.z * invN - m * m; sc = g0.z * rsqrtf(var + BN_EPS);
    o0.z = h0.z + (bflo(p.y) - m) * sc + b0.z;
    m = s0.w * invN; var = q0.w * invN - m * m; sc = g0.w * rsqrtf(var + BN_EPS);
    o0.w = h0.w + (bfhi(p.y) - m) * sc + b0.w;

    m = s1.x * invN; var = q1.x * invN - m * m; sc = g1.x * rsqrtf(var + BN_EPS);
    o1.x = h1.x + (bflo(p.z) - m) * sc + b1.x;
    m = s1.y * invN; var = q1.y * invN - m * m; sc = g1.y * rsqrtf(var + BN_EPS);
    o1.y = h1.y + (bfhi(p.z) - m) * sc + b1.y;
    m = s1.z * invN; var = q1.z * invN - m * m; sc = g1.z * rsqrtf(var + BN_EPS);
    o1.z = h1.z + (bflo(p.w) - m) * sc + b1.z;
    m = s1.w * invN; var = q1.w * invN - m * m; sc = g1.w * rsqrtf(var + BN_EPS);
    o1.w = h1.w + (bfhi(p.w) - m) * sc + b1.w;

    out4[2 * idx]     = o0;
    out4[2 * idx + 1] = o1;
}

// ---------------------------------------------------------------------------
extern "C" void kernel_launch(void* const* d_in, const int* in_sizes, int n_in,
                              void* d_out, int out_size, void* d_ws, size_t ws_size,
                              hipStream_t stream) {
    const float* h      = (const float*)d_in[0];
    const float* snorm  = (const float*)d_in[1];
    const float* Wself  = (const float*)d_in[2];
    const float* Wneigh = (const float*)d_in[3];
    const float* bias   = (const float*)d_in[4];
    const float* gamma  = (const float*)d_in[5];
    const float* beta   = (const float*)d_in[6];
    const int*   src    = (const int*)d_in[7];
    const int*   dst    = (const int*)d_in[8];
    float* out = (float*)d_out;

    // ws layout:
    // zeroed:   [ cursor : N int ][ sums : D f ][ sumsq : D f ]
    // unzeroed: [ esrc : N*CAP int = 20.5MB ][ wfrag : 64KB ]
    //           [ hb : 10.2MB ][ preb : 10.2MB ][ hb8 : 5.1MB ]
    int*   cursor = (int*)d_ws;
    float* sums   = (float*)(cursor + N_NODES);
    float* sumsq  = sums + D;
    int*   esrc   = (int*)(sumsq + D);
    size_t off    = (size_t)((char*)(esrc + (size_t)N_NODES * CAP) - (char*)d_ws);
    off = (off + 15) & ~(size_t)15;
    uint4* wfrag = (uint4*)((char*)d_ws + off);
    uint4* hb4   = wfrag + 4096;
    ushort* preb = (ushort*)(hb4 + N_NODES * (D / 8));
    uint2* hb8   = (uint2*)(preb + (size_t)N_NODES * D);

    size_t zero_bytes = (size_t)(N_NODES + 2 * D) * sizeof(float);
    hipMemsetAsync(d_ws, 0, zero_bytes, stream);

    // K1: colored bucket fill + h -> bf16/fp8 + W -> frag-major bf16
    cvt_fill_kernel<<<FILL_BLOCKS, 256, 0, stream>>>(
        dst, src, cursor, esrc, (const float4*)h, hb4, hb8, Wself, Wneigh, wfrag);
    // K2': merged gather + dual GEMM + relu + snorm + BN partials -> preb
    gemm_gather_kernel<<<GG_BLOCKS, 256, 0, stream>>>(
        hb4, (const uint4*)hb8, cursor, esrc, wfrag, snorm, bias,
        preb, sums, sumsq);
    // K4: finalize: residual + BN from bf16 pre -> d_out
    final_kernel<<<(N_NODES * D / 8 + 255) / 256, 256, 0, stream>>>(
        (const float4*)h, (const float4*)sums, (const float4*)sumsq,
        (const float4*)gamma, (const float4*)beta, (const uint4*)preb,
        (float4*)out);
}

// Round 5
// 168.737 us; speedup vs baseline: 1.0912x; 1.0912x over previous
//
#include <hip/hip_runtime.h>
#include <hip/hip_bf16.h>

constexpr int N_NODES = 40000;
constexpr int N_EDGES = 640000;
constexpr int D = 128;
constexpr float BN_EPS = 1e-5f;
constexpr int CAP = 128;          // per-node edge bucket capacity (max deg ~40)
constexpr int NTILES = 1250;      // 625 rowtiles x 2 col-halves
constexpr int NCOLOR = 8;         // XCD colors
constexpr int NODES_PER_COLOR = N_NODES / NCOLOR;   // 5000
constexpr int FILL_BLOCKS = 2560; // 8 colors x 320 ranks
constexpr int COLOR_STRIDE = (FILL_BLOCKS / NCOLOR) * 256;  // 81920
constexpr int NREP = 8;           // BN partial replicas (atomic de-contention)

typedef __attribute__((ext_vector_type(8))) short short8;
typedef __attribute__((ext_vector_type(4))) float f32x4;
typedef __attribute__((ext_vector_type(2))) float f32x2;

__device__ __forceinline__ unsigned bf16_rne(float f) {
    unsigned b = __float_as_uint(f);
    return (b + 0x7FFFu + ((b >> 16) & 1u)) >> 16;
}
__device__ __forceinline__ float bflo(unsigned w) { return __uint_as_float(w << 16); }
__device__ __forceinline__ float bfhi(unsigned w) { return __uint_as_float(w & 0xFFFF0000u); }

// ---------------------------------------------------------------------------
// K1: fused h->bf16 + h->fp8 / W->frag-major conversion + XCD-COLORED bucket
// fill. (unchanged from round 3 / 172.7us version)
// ---------------------------------------------------------------------------
__global__ __launch_bounds__(256) void cvt_fill_kernel(
        const int* __restrict__ dst,
        const int* __restrict__ src,
        int* __restrict__ cursor,
        int* __restrict__ esrc,
        const float4* __restrict__ h4,
        uint4* __restrict__ hb4,
        uint2* __restrict__ hb8,
        const float* __restrict__ Wself,
        const float* __restrict__ Wneigh,
        uint4* __restrict__ wfrag) {
    int gid = blockIdx.x * blockDim.x + threadIdx.x;

    if (gid < N_EDGES) {
        float4 a = h4[2 * gid];
        float4 b = h4[2 * gid + 1];
        uint4 o;
        o.x = bf16_rne(a.x) | (bf16_rne(a.y) << 16);
        o.y = bf16_rne(a.z) | (bf16_rne(a.w) << 16);
        o.z = bf16_rne(b.x) | (bf16_rne(b.y) << 16);
        o.w = bf16_rne(b.z) | (bf16_rne(b.w) << 16);
        hb4[gid] = o;
        unsigned w0 = __builtin_amdgcn_cvt_pk_fp8_f32(a.x, a.y, 0, false);
        w0 = __builtin_amdgcn_cvt_pk_fp8_f32(a.z, a.w, w0, true);
        unsigned w1 = __builtin_amdgcn_cvt_pk_fp8_f32(b.x, b.y, 0, false);
        w1 = __builtin_amdgcn_cvt_pk_fp8_f32(b.z, b.w, w1, true);
        uint2 o8; o8.x = w0; o8.y = w1;
        hb8[gid] = o8;
    }
    // W -> frag-major bf16: granule G=(ct*8+kt)*64+kg*16+n holds j=0..7 of
    // Wcat[k=kt*32+kg*8+j][col=ct*16+n], Wcat=[Wself;Wneigh] (K=256).
    if (gid < 4096) {
        int G = gid;
        int l = G & 63;
        int tile = G >> 6;
        int kg = l >> 4, n = l & 15;
        int ct = tile >> 3, kt = tile & 7;
        int k0 = kt * 32 + kg * 8;
        int col = ct * 16 + n;
        unsigned w[8];
        #pragma unroll
        for (int j = 0; j < 8; j++) {
            int k = k0 + j;
            float v = (k < D) ? Wself[(size_t)k * D + col]
                              : Wneigh[(size_t)(k - D) * D + col];
            w[j] = bf16_rne(v);
        }
        uint4 ow;
        ow.x = w[0] | (w[1] << 16);
        ow.y = w[2] | (w[3] << 16);
        ow.z = w[4] | (w[5] << 16);
        ow.w = w[6] | (w[7] << 16);
        wfrag[G] = ow;
    }

    // colored bucket fill
    int c = blockIdx.x & (NCOLOR - 1);
    int lo = c * NODES_PER_COLOR;
    int hi = lo + NODES_PER_COLOR;
    int base = (blockIdx.x >> 3) * 256 + threadIdx.x;
    for (int e = base; e < N_EDGES; e += COLOR_STRIDE) {
        int t = dst[e];
        if (t >= lo && t < hi) {
            int s = src[e];
            int p = atomicAdd(&cursor[t], 1);
            if (p < CAP) esrc[t * CAP + p] = s;
        }
    }
}

// ---------------------------------------------------------------------------
// K2: gather + mean from fp8 rows, one wave per node, COLOR-PINNED.
// (unchanged from round 3)
// ---------------------------------------------------------------------------
__global__ __launch_bounds__(256) void gather_kernel(
        const uint4* __restrict__ hb8q,   // 8 uint4 per node row (128 fp8)
        const int* __restrict__ cursor,
        const int* __restrict__ esrc,
        uint4* __restrict__ hnb4) {
    int c = blockIdx.x & (NCOLOR - 1);
    int rank = blockIdx.x >> 3;           // 0..1249
    int wid = threadIdx.x >> 6;
    int node = c * NODES_PER_COLOR + rank * 4 + wid;
    int lane = threadIdx.x & 63;
    int g  = lane & 7;        // 16-col group
    int es = lane >> 3;       // 8 edge slices
    int deg = cursor[node];
    int cnt = deg < CAP ? deg : CAP;
    const int* bucket = esrc + node * CAP;
    float acc[16];
    #pragma unroll
    for (int i = 0; i < 16; i++) acc[i] = 0.f;
    for (int j = es; j < cnt; j += 8) {
        int a = bucket[j];
        uint4 v = hb8q[(size_t)a * 8 + g];
        f32x2 f;
        f = __builtin_amdgcn_cvt_pk_f32_fp8(v.x, false); acc[0]  += f.x; acc[1]  += f.y;
        f = __builtin_amdgcn_cvt_pk_f32_fp8(v.x, true);  acc[2]  += f.x; acc[3]  += f.y;
        f = __builtin_amdgcn_cvt_pk_f32_fp8(v.y, false); acc[4]  += f.x; acc[5]  += f.y;
        f = __builtin_amdgcn_cvt_pk_f32_fp8(v.y, true);  acc[6]  += f.x; acc[7]  += f.y;
        f = __builtin_amdgcn_cvt_pk_f32_fp8(v.z, false); acc[8]  += f.x; acc[9]  += f.y;
        f = __builtin_amdgcn_cvt_pk_f32_fp8(v.z, true);  acc[10] += f.x; acc[11] += f.y;
        f = __builtin_amdgcn_cvt_pk_f32_fp8(v.w, false); acc[12] += f.x; acc[13] += f.y;
        f = __builtin_amdgcn_cvt_pk_f32_fp8(v.w, true);  acc[14] += f.x; acc[15] += f.y;
    }
    #pragma unroll
    for (int i = 0; i < 16; i++) {
        acc[i] += __shfl_xor(acc[i], 8);
        acc[i] += __shfl_xor(acc[i], 16);
        acc[i] += __shfl_xor(acc[i], 32);
    }
    if (es == 0) {
        float rd = 1.0f / (float)(deg > 1 ? deg : 1);
        uint4 o0, o1;
        o0.x = bf16_rne(acc[0] * rd)  | (bf16_rne(acc[1] * rd)  << 16);
        o0.y = bf16_rne(acc[2] * rd)  | (bf16_rne(acc[3] * rd)  << 16);
        o0.z = bf16_rne(acc[4] * rd)  | (bf16_rne(acc[5] * rd)  << 16);
        o0.w = bf16_rne(acc[6] * rd)  | (bf16_rne(acc[7] * rd)  << 16);
        o1.x = bf16_rne(acc[8] * rd)  | (bf16_rne(acc[9] * rd)  << 16);
        o1.y = bf16_rne(acc[10] * rd) | (bf16_rne(acc[11] * rd) << 16);
        o1.z = bf16_rne(acc[12] * rd) | (bf16_rne(acc[13] * rd) << 16);
        o1.w = bf16_rne(acc[14] * rd) | (bf16_rne(acc[15] * rd) << 16);
        hnb4[(size_t)node * 16 + g * 2]     = o0;
        hnb4[(size_t)node * 16 + g * 2 + 1] = o1;
    }
}

// ---------------------------------------------------------------------------
// K3: MFMA dual GEMM. Same as round 3 EXCEPT: BN partials go to REPLICATED
// arrays sums_r[8][128]/sumsq_r[8][128] (replica = blockIdx&7, matching the
// XCD round-robin). 8x fewer atomics per cache line -> kills the
// atomic-retire tail that serialized the dispatch end.
// ---------------------------------------------------------------------------
__global__ __launch_bounds__(256) void gemm_kernel(
        const uint4* __restrict__ hb4,
        const uint4* __restrict__ hnb4,
        const uint4* __restrict__ wfrag,
        const float* __restrict__ snorm,
        const float* __restrict__ bias,
        ushort* __restrict__ preb,          // bf16 pre (ws)
        float* __restrict__ sums_r,         // [NREP][D]
        float* __restrict__ sumsq_r) {      // [NREP][D]
    __shared__ uint4 ldsW[2048];
    __shared__ float sums_l[64];
    __shared__ float sumsq_l[64];

    int t = threadIdx.x;
    int lane = t & 63;
    int wid = t >> 6;
    int n = lane & 15;
    int kg = lane >> 4;
    int rowtile = blockIdx.x >> 1;
    int cbt = blockIdx.x & 1;
    int cb = cbt * 64;
    int row_base = rowtile * 64 + wid * 16;
    int row = row_base + n;

    if (t < 64) { sums_l[t] = 0.f; sumsq_l[t] = 0.f; }

    short8 a[8];
    #pragma unroll
    for (int kt = 0; kt < 4; kt++) {
        uint4 v = hb4[(size_t)row * 16 + kt * 4 + kg];
        a[kt] = __builtin_bit_cast(short8, v);
    }
    #pragma unroll
    for (int kt = 0; kt < 4; kt++) {
        uint4 v = hnb4[(size_t)row * 16 + kt * 4 + kg];
        a[4 + kt] = __builtin_bit_cast(short8, v);
    }

    #pragma unroll
    for (int i = 0; i < 8; i++) {
        int g = i * 256 + t;
        ldsW[g] = wfrag[cbt * 2048 + g];
    }
    __syncthreads();

    f32x4 acc[4];
    #pragma unroll
    for (int lt = 0; lt < 4; lt++) acc[lt] = (f32x4){0.f, 0.f, 0.f, 0.f};
    #pragma unroll
    for (int lt = 0; lt < 4; lt++) {
        #pragma unroll
        for (int kt = 0; kt < 8; kt++) {
            short8 b = __builtin_bit_cast(short8, ldsW[(lt * 8 + kt) * 64 + lane]);
            acc[lt] = __builtin_amdgcn_mfma_f32_16x16x32_bf16(a[kt], b, acc[lt], 0, 0, 0);
        }
    }

    float snv[4];
    #pragma unroll
    for (int r = 0; r < 4; r++) snv[r] = snorm[row_base + kg * 4 + r];

    #pragma unroll
    for (int lt = 0; lt < 4; lt++) {
        int col = cb + lt * 16 + n;
        float bb = bias[col];
        float csum = 0.f, csq = 0.f;
        #pragma unroll
        for (int r = 0; r < 4; r++) {
            int rr = row_base + kg * 4 + r;
            float v = acc[lt][r] + bb;
            v = fmaxf(v, 0.f);
            v *= snv[r];
            preb[(size_t)rr * D + col] = (ushort)bf16_rne(v);
            csum += v;
            csq += v * v;
        }
        csum += __shfl_xor(csum, 16); csq += __shfl_xor(csq, 16);
        csum += __shfl_xor(csum, 32); csq += __shfl_xor(csq, 32);
        if (kg == 0) {
            atomicAdd(&sums_l[lt * 16 + n], csum);
            atomicAdd(&sumsq_l[lt * 16 + n], csq);
        }
    }
    __syncthreads();
    if (t < 64) {
        int rep = blockIdx.x & (NREP - 1);
        atomicAdd(&sums_r[rep * D + cb + t], sums_l[t]);
        atomicAdd(&sumsq_r[rep * D + cb + t], sumsq_l[t]);
    }
}

// ---------------------------------------------------------------------------
// K4: finalize: out = h + (pre - mean)*scale + beta; reduces the NREP
// replica partials per column first (tiny, L2-broadcast).
// ---------------------------------------------------------------------------
__global__ __launch_bounds__(256) void final_kernel(
        const float4* __restrict__ h4,
        const float4* __restrict__ sums_r4,    // [NREP][32] float4
        const float4* __restrict__ sumsq_r4,   // [NREP][32] float4
        const float4* __restrict__ gamma4,
        const float4* __restrict__ beta4,
        const uint4* __restrict__ preb4,
        float4* __restrict__ out4) {
    int idx = blockIdx.x * blockDim.x + threadIdx.x;
    int total = N_NODES * D / 8;
    if (idx >= total) return;
    int g = idx & 15;                       // col-group of 8 within the row
    const float invN = 1.0f / (float)N_NODES;

    float4 s0 = {0.f,0.f,0.f,0.f}, s1 = {0.f,0.f,0.f,0.f};
    float4 q0 = {0.f,0.f,0.f,0.f}, q1 = {0.f,0.f,0.f,0.f};
    #pragma unroll
    for (int r = 0; r < NREP; r++) {
        float4 a0 = sums_r4[r * 32 + 2 * g],  a1 = sums_r4[r * 32 + 2 * g + 1];
        float4 c0 = sumsq_r4[r * 32 + 2 * g], c1 = sumsq_r4[r * 32 + 2 * g + 1];
        s0.x += a0.x; s0.y += a0.y; s0.z += a0.z; s0.w += a0.w;
        s1.x += a1.x; s1.y += a1.y; s1.z += a1.z; s1.w += a1.w;
        q0.x += c0.x; q0.y += c0.y; q0.z += c0.z; q0.w += c0.w;
        q1.x += c1.x; q1.y += c1.y; q1.z += c1.z; q1.w += c1.w;
    }

    float4 g0 = gamma4[2 * g], g1 = gamma4[2 * g + 1];
    float4 b0 = beta4[2 * g],  b1 = beta4[2 * g + 1];

    uint4 p = preb4[idx];
    float4 h0 = h4[2 * idx], h1 = h4[2 * idx + 1];
    float4 o0, o1;
    float m, var, sc;

    m = s0.x * invN; var = q0.x * invN - m * m; sc = g0.x * rsqrtf(var + BN_EPS);
    o0.x = h0.x + (bflo(p.x) - m) * sc + b0.x;
    m = s0.y * invN; var = q0.y * invN - m * m; sc = g0.y * rsqrtf(var + BN_EPS);
    o0.y = h0.y + (bfhi(p.x) - m) * sc + b0.y;
    m = s0.z * invN; var = q0.z * invN - m * m; sc = g0.z * rsqrtf(var + BN_EPS);
    o0.z = h0.z + (bflo(p.y) - m) * sc + b0.z;
    m = s0.w * invN; var = q0.w * invN - m * m; sc = g0.w * rsqrtf(var + BN_EPS);
    o0.w = h0.w + (bfhi(p.y) - m) * sc + b0.w;

    m = s1.x * invN; var = q1.x * invN - m * m; sc = g1.x * rsqrtf(var + BN_EPS);
    o1.x = h1.x + (bflo(p.z) - m) * sc + b1.x;
    m = s1.y * invN; var = q1.y * invN - m * m; sc = g1.y * rsqrtf(var + BN_EPS);
    o1.y = h1.y + (bfhi(p.z) - m) * sc + b1.y;
    m = s1.z * invN; var = q1.z * invN - m * m; sc = g1.z * rsqrtf(var + BN_EPS);
    o1.z = h1.z + (bflo(p.w) - m) * sc + b1.z;
    m = s1.w * invN; var = q1.w * invN - m * m; sc = g1.w * rsqrtf(var + BN_EPS);
    o1.w = h1.w + (bfhi(p.w) - m) * sc + b1.w;

    out4[2 * idx]     = o0;
    out4[2 * idx + 1] = o1;
}

// ---------------------------------------------------------------------------
extern "C" void kernel_launch(void* const* d_in, const int* in_sizes, int n_in,
                              void* d_out, int out_size, void* d_ws, size_t ws_size,
                              hipStream_t stream) {
    const float* h      = (const float*)d_in[0];
    const float* snorm  = (const float*)d_in[1];
    const float* Wself  = (const float*)d_in[2];
    const float* Wneigh = (const float*)d_in[3];
    const float* bias   = (const float*)d_in[4];
    const float* gamma  = (const float*)d_in[5];
    const float* beta   = (const float*)d_in[6];
    const int*   src    = (const int*)d_in[7];
    const int*   dst    = (const int*)d_in[8];
    float* out = (float*)d_out;

    // ws layout:
    // zeroed:   [ cursor : N int ][ sums_r : 8*D f ][ sumsq_r : 8*D f ]
    // unzeroed: [ esrc : N*CAP int = 20.5MB ][ wfrag : 64KB ]
    //           [ hb : 10.2MB ][ hnb : 10.2MB ][ preb : 10.2MB ][ hb8 : 5.1MB ]
    int*   cursor  = (int*)d_ws;
    float* sums_r  = (float*)(cursor + N_NODES);
    float* sumsq_r = sums_r + NREP * D;
    int*   esrc    = (int*)(sumsq_r + NREP * D);
    size_t off     = (size_t)((char*)(esrc + (size_t)N_NODES * CAP) - (char*)d_ws);
    off = (off + 15) & ~(size_t)15;
    uint4* wfrag = (uint4*)((char*)d_ws + off);
    uint4* hb4   = wfrag + 4096;
    uint4* hnb4  = hb4 + N_NODES * (D / 8);
    ushort* preb = (ushort*)(hnb4 + N_NODES * (D / 8));
    uint2* hb8   = (uint2*)(preb + (size_t)N_NODES * D);

    size_t zero_bytes = (size_t)(N_NODES + 2 * NREP * D) * sizeof(float);
    hipMemsetAsync(d_ws, 0, zero_bytes, stream);

    // K1: colored bucket fill + h -> bf16/fp8 + W -> frag-major bf16
    cvt_fill_kernel<<<FILL_BLOCKS, 256, 0, stream>>>(
        dst, src, cursor, esrc, (const float4*)h, hb4, hb8, Wself, Wneigh, wfrag);
    // K2: gather + mean from fp8 -> hnb (bf16), one wave per node, color-pinned
    gather_kernel<<<N_NODES / 4, 256, 0, stream>>>(
        (const uint4*)hb8, cursor, esrc, hnb4);
    // K3: MFMA dual GEMM + relu + snorm + BN partials (8 replicas) -> preb
    gemm_kernel<<<NTILES, 256, 0, stream>>>(hb4, hnb4, wfrag, snorm, bias,
                                            preb, sums_r, sumsq_r);
    // K4: finalize: replica-reduce + residual + BN -> d_out
    final_kernel<<<(N_NODES * D / 8 + 255) / 256, 256, 0, stream>>>(
        (const float4*)h, (const float4*)sums_r, (const float4*)sumsq_r,
        (const float4*)gamma, (const float4*)beta, (const uint4*)preb,
        (float4*)out);
}